// Round 10
// baseline (124.131 us; speedup 1.0000x reference)
//
#include <hip/hip_runtime.h>
#include <math.h>

// Problem constants (from reference setup_inputs)
#define BS 64      // batch
#define F  256     // features (K of the Gram matmul)
#define M  128     // columns  (M=N of the Gram matmul)
#define MF (M * F) // u16 elements per matrix in hT
#define NBP 1056   // (a, b-pair) tiles per mat; grid = 2112 = 8 * 264

typedef unsigned short u16;
typedef _Float16 f16x8 __attribute__((ext_vector_type(8)));
typedef float    f32x16 __attribute__((ext_vector_type(16)));

typedef const __attribute__((address_space(1))) void gas_t;
typedef __attribute__((address_space(3))) void las_t;

// ---------------------------------------------------------------------------
// Pre-pass: fp32 [f][m] -> fp16 GRANULE-MAJOR hT[b][f8][m][8].
// ---------------------------------------------------------------------------
__global__ __launch_bounds__(256) void convert_f16_kernel(
    const float* __restrict__ m1, const float* __restrict__ m2,
    u16* __restrict__ hT)
{
    __shared__ float tile[64 * M];   // 32 KB
    const int mat = blockIdx.x >> 6;
    const int b   = blockIdx.x & 63;
    const int f0  = blockIdx.y * 64;
    const float* src = (mat == 0 ? m1 : m2) + (size_t)b * MF + (size_t)f0 * M;
    const int tid = threadIdx.x;

    const float4* g = (const float4*)src;
    float4* s = (float4*)tile;
    #pragma unroll
    for (int i = 0; i < 8; ++i)
        s[tid + i * 256] = g[tid + i * 256];
    __syncthreads();

    const size_t obase = ((size_t)(mat * BS + b) * 32 + (f0 >> 3)) * 1024;
    #pragma unroll
    for (int it = 0; it < 4; ++it) {
        const int idx = it * 256 + tid;
        const int f8l = idx >> 7;
        const int m   = idx & 127;
        u16 hh[8] __attribute__((aligned(16)));
        #pragma unroll
        for (int j = 0; j < 8; ++j) {
            const float x = tile[(f8l * 8 + j) * M + m];  // 2 lanes/bank: free
            const _Float16 h = (_Float16)x;               // RNE
            hh[j] = __builtin_bit_cast(u16, h);
        }
        *(uint4*)&hT[obase + (size_t)idx * 8] = *(const uint4*)hh;
    }
}

// ---------------------------------------------------------------------------
// ROUND 18: DMA STAGING + COUNTED VMCNT (the m201 discipline). Fitted fact
// across ALL prior rounds: per-CU global-return rate saturates at 12-16
// B/cyc/CU whenever loads return through the VGPR writeback path (reg-staged
// or direct fragments), regardless of waves/barriers/prefetch-depth/cache
// level (r16: outstanding x2.7 -> rate unchanged = rate-saturated, not
// latency-starved). Existence proof that this is NOT a chip ceiling: m201's
// 8-phase GEMM stages ~20 B/cyc/CU, HK ~24, both via global_load_lds DMA +
// counted s_waitcnt vmcnt(N) + raw s_barrier (never vmcnt(0) in-loop). Our
// only gload_lds try (r15) was invalidated by __syncthreads draining the
// DMA queue each chunk (prefetch depth 0).
// THIS ROUND: pair-sharing (a,b1,b2) = the 405 MB register-feasible byte
// floor, 512T/8 waves, wave (pp,q) owns a 64x64 quadrant of matrix
// (a,b_pp): acc = 64 AGPR, no staging VGPRs (DMA) -> target <=64 arch VGPR
// -> 4 waves/SIMD -> 2 blocks/CU = 16 waves/CU. Staging: 24 KB/chunk = 24
// 1KB DMA segments, 3 per wave; 3-buffer LDS ring (72 KB), 2-deep prefetch;
// per chunk: vmcnt(3) [counted: next chunk stays in flight across the
// barrier] -> raw s_barrier -> sched_barrier(0) -> 8 MFMA (setprio) ->
// sched_barrier(0) -> issue chunk s+2 into buf (s+2)%3. ONE barrier/chunk.
// Ring safety: the iter-s barrier means all waves finished iter s-1's
// reads of buf (s+2)%3 before any wave's s+2 DMA targets it.
// Read-out: gram 30-42 = DMA path escapes the cap; gram ~53 = cap is
// path-independent -> we are at the byte-floor/rate roofline (declare).
// ---------------------------------------------------------------------------

#define ISSUE(S, TB) {                                                        \
    __builtin_amdgcn_global_load_lds((gas_t*)(src0 + (S) * 4096),             \
        (las_t*)&lds[(TB) + dst0], 16, 0, 0);                                 \
    __builtin_amdgcn_global_load_lds((gas_t*)(src1 + (S) * 4096),             \
        (las_t*)&lds[(TB) + dst1], 16, 0, 0);                                 \
    __builtin_amdgcn_global_load_lds((gas_t*)(src2 + (S) * 4096),             \
        (las_t*)&lds[(TB) + dst2], 16, 0, 0);                                 \
}

#define DOCHUNK(S) {                                                          \
    if ((S) < 7) { asm volatile("s_waitcnt vmcnt(3)" ::: "memory"); }         \
    else         { asm volatile("s_waitcnt vmcnt(0)" ::: "memory"); }         \
    __builtin_amdgcn_s_barrier();                                             \
    __builtin_amdgcn_sched_barrier(0);                                        \
    {                                                                         \
        const int bu = ((S) % 3) * 12288;                                     \
        __builtin_amdgcn_s_setprio(1);                                        \
        _Pragma("unroll")                                                     \
        for (int kk = 0; kk < 2; ++kk) {                                      \
            const int kb = bu + kk * 2048 + lhalf * 1024;                     \
            const f16x8 a0 = *(const f16x8*)&lds[kb + qr * 512 + l31 * 8];    \
            const f16x8 a1 = *(const f16x8*)&lds[kb + qr * 512 + 256 + l31 * 8]; \
            const f16x8 b0 = *(const f16x8*)&lds[kb + brow + qc * 512 + l31 * 8]; \
            const f16x8 b1 = *(const f16x8*)&lds[kb + brow + qc * 512 + 256 + l31 * 8]; \
            acc[0][0] = __builtin_amdgcn_mfma_f32_32x32x16_f16(a0, b0, acc[0][0], 0, 0, 0); \
            acc[0][1] = __builtin_amdgcn_mfma_f32_32x32x16_f16(a0, b1, acc[0][1], 0, 0, 0); \
            acc[1][0] = __builtin_amdgcn_mfma_f32_32x32x16_f16(a1, b0, acc[1][0], 0, 0, 0); \
            acc[1][1] = __builtin_amdgcn_mfma_f32_32x32x16_f16(a1, b1, acc[1][1], 0, 0, 0); \
        }                                                                     \
        __builtin_amdgcn_s_setprio(0);                                        \
    }                                                                         \
    __builtin_amdgcn_sched_barrier(0);                                        \
    if ((S) <= 5) { ISSUE((S) + 2, (((S) + 2) % 3) * 12288); }                \
}

__global__ __launch_bounds__(512, 4) void gram_hist_mfma(
    const u16* __restrict__ hT, float* __restrict__ out)
{
    // 3 ring bufs x [A | B1 | B2] x 4096 u16 = 72 KB.
    __shared__ u16 lds[3 * 12288];
    __shared__ float smin[8], smax[8];
    __shared__ int hist[2][8];

    const int tid  = threadIdx.x;
    const int lane = tid & 63;
    const int w    = tid >> 6;       // 0..7

    if (tid < 16) hist[tid >> 3][tid & 7] = 0;

    // XCD-pinned mapping: 2112 blocks = 8 XCDs x 264 slots (r14: HBM -2.5x).
    const int bid  = blockIdx.x;
    const int xcd  = bid & 7;
    const int mat  = xcd >> 2;
    int p = (xcd & 3) * 264 + (bid >> 3);
    // Decode tile p -> (a, pair) with per-a count ceil((64-a)/2).
    int a = 0;
    { int cnt = 32; while (p >= cnt) { p -= cnt; ++a; cnt = (64 - a + 1) >> 1; } }
    const int b1 = a + 2 * p;
    int b2 = b1 + 1;
    const bool b2valid = (b2 <= 63);
    if (!b2valid) b2 = b1;          // duplicate work, writes suppressed

    const int pp = w >> 2;           // pair (0: b1, 1: b2)
    const int q  = w & 3;            // quadrant of the 128x128 matrix
    const int qr = q >> 1;           // 64-row half
    const int qc = q & 1;            // 64-col half
    const int l31   = lane & 31;
    const int lhalf = lane >> 5;
    const int brow  = (1 + pp) * 4096;   // B row slot in a ring buf (u16)

    // DMA segment assignment: 24 segments/chunk (row 0..2 x sub 0..7);
    // wave w owns g = 3w..3w+2. Global src is PER-LANE (+lane*8 u16 = 16B);
    // LDS dst is WAVE-UNIFORM (HW adds lane*16B).
    const int g0 = w * 3, g1 = w * 3 + 1, g2 = w * 3 + 2;
    const int r0_ = g0 >> 3, r1_ = g1 >> 3, r2_ = g2 >> 3;
    const int s0_ = g0 & 7,  s1_ = g1 & 7,  s2_ = g2 & 7;
    const int row0 = (r0_ == 0) ? a : (r0_ == 1 ? b1 : b2);
    const int row1 = (r1_ == 0) ? a : (r1_ == 1 ? b1 : b2);
    const int row2 = (r2_ == 0) ? a : (r2_ == 1 ? b1 : b2);
    const u16* src0 = hT + (size_t)(mat * BS + row0) * MF + s0_ * 512 + lane * 8;
    const u16* src1 = hT + (size_t)(mat * BS + row1) * MF + s1_ * 512 + lane * 8;
    const u16* src2 = hT + (size_t)(mat * BS + row2) * MF + s2_ * 512 + lane * 8;
    const int dst0 = r0_ * 4096 + s0_ * 512;   // u16 units within a ring buf
    const int dst1 = r1_ * 4096 + s1_ * 512;
    const int dst2 = r2_ * 4096 + s2_ * 512;

    f32x16 acc[2][2];
    #pragma unroll
    for (int t = 0; t < 2; ++t)
        #pragma unroll
        for (int u = 0; u < 2; ++u)
            #pragma unroll
            for (int r = 0; r < 16; ++r) acc[t][u][r] = 0.0f;

    // ---- prologue: issue chunks 0,1 (2-deep); vmcnt counts 6/wave ----
    ISSUE(0, 0);
    ISSUE(1, 12288);

    // ---- 8 chunks, counted-vmcnt ring pipeline ----
    DOCHUNK(0); DOCHUNK(1); DOCHUNK(2); DOCHUNK(3);
    DOCHUNK(4); DOCHUNK(5); DOCHUNK(6); DOCHUNK(7);

    // ---- epilogue: matrix pp owned by waves pp*4 .. pp*4+3 ----
    float vmin = acc[0][0][0], vmax = vmin;
    #pragma unroll
    for (int t = 0; t < 2; ++t)
        #pragma unroll
        for (int u = 0; u < 2; ++u)
            #pragma unroll
            for (int r = 0; r < 16; ++r) {
                vmin = fminf(vmin, acc[t][u][r]);
                vmax = fmaxf(vmax, acc[t][u][r]);
            }
    #pragma unroll
    for (int off = 1; off < 64; off <<= 1) {
        vmin = fminf(vmin, __shfl_xor(vmin, off, 64));
        vmax = fmaxf(vmax, __shfl_xor(vmax, off, 64));
    }
    if (lane == 0) { smin[w] = vmin; smax[w] = vmax; }
    __syncthreads();
    const int p4 = pp * 4;
    const float pmn = fminf(fminf(smin[p4], smin[p4 + 1]),
                            fminf(smin[p4 + 2], smin[p4 + 3]));
    const float pmx = fmaxf(fmaxf(smax[p4], smax[p4 + 1]),
                            fmaxf(smax[p4 + 2], smax[p4 + 3]));
    const float denom = (pmx > pmn) ? (pmx - pmn) : 1.0f;
    const float scale = 8.0f / denom;
    const float bias  = -pmn * scale;

    // per-thread packed histogram: 64 values -> 8-bit fields (<=64/bin)
    unsigned w0 = 0, w1 = 0;
    #pragma unroll
    for (int t = 0; t < 2; ++t)
        #pragma unroll
        for (int u = 0; u < 2; ++u)
            #pragma unroll
            for (int r = 0; r < 16; ++r) {
                const float tv = fmaf(acc[t][u][r], scale, bias);
                int k = (int)tv;         // tv >= -eps; trunc == floor
                k = k > 7 ? 7 : k;
                const unsigned inc = 1u << ((k & 3) * 8);
                if (k < 4) w0 += inc; else w1 += inc;
            }
    unsigned e0 = (w0 & 0xFFu)         | (((w0 >> 8)  & 0xFFu) << 16);
    unsigned e1 = ((w0 >> 16) & 0xFFu) | (((w0 >> 24) & 0xFFu) << 16);
    unsigned e2 = (w1 & 0xFFu)         | (((w1 >> 8)  & 0xFFu) << 16);
    unsigned e3 = ((w1 >> 16) & 0xFFu) | (((w1 >> 24) & 0xFFu) << 16);
    #pragma unroll
    for (int off = 32; off > 0; off >>= 1) {
        e0 += __shfl_down(e0, off, 64);
        e1 += __shfl_down(e1, off, 64);
        e2 += __shfl_down(e2, off, 64);
        e3 += __shfl_down(e3, off, 64);
    }
    if (lane == 0) {
        atomicAdd(&hist[pp][0], (int)(e0 & 0xFFFFu)); atomicAdd(&hist[pp][1], (int)(e0 >> 16));
        atomicAdd(&hist[pp][2], (int)(e1 & 0xFFFFu)); atomicAdd(&hist[pp][3], (int)(e1 >> 16));
        atomicAdd(&hist[pp][4], (int)(e2 & 0xFFFFu)); atomicAdd(&hist[pp][5], (int)(e2 >> 16));
        atomicAdd(&hist[pp][6], (int)(e3 & 0xFFFFu)); atomicAdd(&hist[pp][7], (int)(e3 >> 16));
    }
    __syncthreads();

    // q==0 wave of each pair normalizes and writes both symmetric rows
    const int B = (pp == 0) ? b1 : b2;
    const bool valid = (pp == 0) || b2valid;
    if (valid && q == 0 && lane < 8) {
        float ss = 0.0f;
        #pragma unroll
        for (int k = 0; k < 8; ++k) {
            const float cc = (float)hist[pp][k];
            ss += cc * cc;
        }
        const float nrm = fmaxf(sqrtf(ss), 1e-12f);
        const float v = (float)hist[pp][lane] / nrm;
        out[((size_t)a * BS + B) * 16 + mat * 8 + lane] = v;
        if (a != B)
            out[((size_t)B * BS + a) * 16 + mat * 8 + lane] = v;
    }
}

extern "C" void kernel_launch(void* const* d_in, const int* in_sizes, int n_in,
                              void* d_out, int out_size, void* d_ws, size_t ws_size,
                              hipStream_t stream) {
    const float* m1 = (const float*)d_in[0];
    const float* m2 = (const float*)d_in[1];
    float* out = (float*)d_out;

    // Workspace: granule-major fp16 array, 2*64*128*256 u16 = 8.39 MB.
    u16* hT = (u16*)d_ws;

    convert_f16_kernel<<<dim3(128, 4), 256, 0, stream>>>(m1, m2, hT);
    gram_hist_mfma<<<2 * NBP, 512, 0, stream>>>(hT, out);
}

// Round 11
// 120.697 us; speedup vs baseline: 1.0285x; 1.0285x over previous
//
#include <hip/hip_runtime.h>
#include <math.h>

// Problem constants (from reference setup_inputs)
#define BS 64      // batch
#define F  256     // features (K of the Gram matmul)
#define M  128     // columns  (M=N of the Gram matmul)
#define MF (M * F) // u16 elements per matrix in hT
#define NBP 1056   // (a, b-pair) tiles per mat; grid = 2112 = 8 * 264

typedef unsigned short u16;
typedef _Float16 f16x8 __attribute__((ext_vector_type(8)));
typedef float    f32x16 __attribute__((ext_vector_type(16)));

typedef const __attribute__((address_space(1))) void gas_t;
typedef __attribute__((address_space(3))) void las_t;

// ---------------------------------------------------------------------------
// Pre-pass: fp32 [f][m] -> fp16 GRANULE-MAJOR hT[b][f8][m][8].
// ---------------------------------------------------------------------------
__global__ __launch_bounds__(256) void convert_f16_kernel(
    const float* __restrict__ m1, const float* __restrict__ m2,
    u16* __restrict__ hT)
{
    __shared__ float tile[64 * M];   // 32 KB
    const int mat = blockIdx.x >> 6;
    const int b   = blockIdx.x & 63;
    const int f0  = blockIdx.y * 64;
    const float* src = (mat == 0 ? m1 : m2) + (size_t)b * MF + (size_t)f0 * M;
    const int tid = threadIdx.x;

    const float4* g = (const float4*)src;
    float4* s = (float4*)tile;
    #pragma unroll
    for (int i = 0; i < 8; ++i)
        s[tid + i * 256] = g[tid + i * 256];
    __syncthreads();

    const size_t obase = ((size_t)(mat * BS + b) * 32 + (f0 >> 3)) * 1024;
    #pragma unroll
    for (int it = 0; it < 4; ++it) {
        const int idx = it * 256 + tid;
        const int f8l = idx >> 7;
        const int m   = idx & 127;
        u16 hh[8] __attribute__((aligned(16)));
        #pragma unroll
        for (int j = 0; j < 8; ++j) {
            const float x = tile[(f8l * 8 + j) * M + m];  // 2 lanes/bank: free
            const _Float16 h = (_Float16)x;               // RNE
            hh[j] = __builtin_bit_cast(u16, h);
        }
        *(uint4*)&hT[obase + (size_t)idx * 8] = *(const uint4*)hh;
    }
}

// ---------------------------------------------------------------------------
// ROUND 19: ALL-DMA STAGING ON THE PROVEN-BEST SHAPE. Model fitting all 11
// experiments: VGPR-returning global loads cap at ~12-14 B/cyc/CU (r9 12.4,
// r17 14.2, m13 chip copy 10.7) = per-CU L1 LINE-FILL throughput (~128B/
// ~10cyc); working set guarantees 0% L1 hits, so every byte pays the fill.
// global_load_lds (TA->LDS direct) bypasses L1: m97/m201 GEMM sustains ~22
// B/cyc/CU through it. Our r15 DMA try was drained by __syncthreads (depth
// 0); r18's was pipeline-starved (16 phase-locked waves, 1 barrier per 8
// MFMAs). THIS ROUND: the r9/r14 53.0-us kernel (256T, 4 waves, wave (pp,c)
// = 128x64 of pair pp, acc 128 AGPR, 2 blocks/CU, pair-sharing = 405 MB
// byte floor) with staging 100% via global_load_lds -- A AND B (B was 2/3
// of the bytes and still went through L1 in r9!). 3-deep LDS ring (3 x
// [A|B1|B2] x 8KB = 72 KB, 2 blocks/CU), 2-chunk DMA prefetch, counted
// s_waitcnt vmcnt(6) (one chunk always in flight), ONE raw s_barrier per
// chunk, 16 MFMAs per barrier, sched_barrier(0) after the wait pins the
// chunk's ds_reads below it (rule 18). Ring safety: buf (S+2)%3 was last
// read in chunk S-1; every wave passed barrier-top-of-S (which follows its
// chunk S-1 reads) before any wave issues chunk S+2 -> no race.
// Read-out: 32-40 us = L1-bypass confirmed; 50-56 us = both paths capped
// -> 405 MB / (256 CU x 13 B/cyc) ~= 51 us IS the roofline; declare next.
// ---------------------------------------------------------------------------

#define ISSUE(S, RB) {                                                        \
    __builtin_amdgcn_global_load_lds((gas_t*)(sp0 + (S) * 4096),              \
        (las_t*)&lds[(RB) + dq0], 16, 0, 0);                                  \
    __builtin_amdgcn_global_load_lds((gas_t*)(sp1 + (S) * 4096),              \
        (las_t*)&lds[(RB) + dq1], 16, 0, 0);                                  \
    __builtin_amdgcn_global_load_lds((gas_t*)(sp2 + (S) * 4096),              \
        (las_t*)&lds[(RB) + dq2], 16, 0, 0);                                  \
    __builtin_amdgcn_global_load_lds((gas_t*)(sp3 + (S) * 4096),              \
        (las_t*)&lds[(RB) + dq3], 16, 0, 0);                                  \
    __builtin_amdgcn_global_load_lds((gas_t*)(sp4 + (S) * 4096),              \
        (las_t*)&lds[(RB) + dq4], 16, 0, 0);                                  \
    __builtin_amdgcn_global_load_lds((gas_t*)(sp5 + (S) * 4096),              \
        (las_t*)&lds[(RB) + dq5], 16, 0, 0);                                  \
}

// One K=32 chunk: wait own 6 DMAs (counted), barrier, 12 ds_read_b128 +
// 16 MFMA, then issue chunk S+2 into the ring (no trailing barrier).
#define DOCHUNK(S) {                                                          \
    if ((S) < 7) { asm volatile("s_waitcnt vmcnt(6)" ::: "memory"); }         \
    else         { asm volatile("s_waitcnt vmcnt(0)" ::: "memory"); }         \
    __builtin_amdgcn_s_barrier();                                             \
    __builtin_amdgcn_sched_barrier(0);                                        \
    {                                                                         \
        const int rb = ((S) % 3) * 12288;                                     \
        __builtin_amdgcn_s_setprio(1);                                        \
        _Pragma("unroll")                                                     \
        for (int kk = 0; kk < 2; ++kk) {                                      \
            const int ab = rb + kk * 2048 + lhalf * 1024 + l31 * 8;           \
            const int bb = rb + brow + kk * 2048 + lhalf * 1024 + c * 512 + l31 * 8; \
            f16x8 af[4], bf[2];                                               \
            _Pragma("unroll")                                                 \
            for (int t = 0; t < 4; ++t)                                       \
                af[t] = *(const f16x8*)&lds[ab + t * 256];                    \
            bf[0] = *(const f16x8*)&lds[bb];                                  \
            bf[1] = *(const f16x8*)&lds[bb + 256];                            \
            _Pragma("unroll")                                                 \
            for (int ti = 0; ti < 4; ++ti) {                                  \
                acc[ti][0] = __builtin_amdgcn_mfma_f32_32x32x16_f16(af[ti], bf[0], acc[ti][0], 0, 0, 0); \
                acc[ti][1] = __builtin_amdgcn_mfma_f32_32x32x16_f16(af[ti], bf[1], acc[ti][1], 0, 0, 0); \
            }                                                                 \
        }                                                                     \
        __builtin_amdgcn_s_setprio(0);                                        \
    }                                                                         \
    if ((S) <= 5) { ISSUE((S) + 2, (((S) + 2) % 3) * 12288); }                \
}

__global__ __launch_bounds__(256, 2) void gram_hist_mfma(
    const u16* __restrict__ hT, float* __restrict__ out)
{
    // Ring: 3 bufs x ([A | B1 | B2] x 4096 u16) = 72 KB.
    __shared__ u16 lds[3 * 12288];
    __shared__ float smin[4], smax[4];
    __shared__ int hist[2][8];

    const int tid  = threadIdx.x;
    const int lane = tid & 63;
    const int w    = tid >> 6;       // 0..3

    if (tid < 16) hist[tid >> 3][tid & 7] = 0;

    // XCD-pinned mapping: 2112 blocks = 8 XCDs x 264 slots (r14: HBM -2.5x).
    const int bid  = blockIdx.x;
    const int xcd  = bid & 7;
    const int mat  = xcd >> 2;
    int p = (xcd & 3) * 264 + (bid >> 3);
    // Decode tile p -> (a, pair) with per-a count ceil((64-a)/2).
    int a = 0;
    { int cnt = 32; while (p >= cnt) { p -= cnt; ++a; cnt = (64 - a + 1) >> 1; } }
    const int b1 = a + 2 * p;
    int b2 = b1 + 1;
    const bool b2valid = (b2 <= 63);
    if (!b2valid) b2 = b1;          // duplicate work, writes suppressed

    const int pp = w >> 1;           // pair (0: b1, 1: b2)
    const int c  = w & 1;            // 64-col half
    const int l31   = lane & 31;
    const int lhalf = lane >> 5;
    const int brow  = (1 + pp) * 4096;   // B row slot within a ring buf (u16)

    // DMA segment assignment: 24 x 1KB segments per chunk (row r 0..2 = a,
    // b1, b2; sub j 0..7). Wave w owns g = 6w..6w+5. Global src PER-LANE
    // (+lane*16B); LDS dst WAVE-UNIFORM (HW adds lane*16B).
    const u16* rowp[3];
    rowp[0] = hT + (size_t)(mat * BS + a)  * MF;
    rowp[1] = hT + (size_t)(mat * BS + b1) * MF;
    rowp[2] = hT + (size_t)(mat * BS + b2) * MF;
    const int g0 = w * 6;
    const u16* sp0 = rowp[(g0 + 0) >> 3] + ((g0 + 0) & 7) * 512 + lane * 8;
    const u16* sp1 = rowp[(g0 + 1) >> 3] + ((g0 + 1) & 7) * 512 + lane * 8;
    const u16* sp2 = rowp[(g0 + 2) >> 3] + ((g0 + 2) & 7) * 512 + lane * 8;
    const u16* sp3 = rowp[(g0 + 3) >> 3] + ((g0 + 3) & 7) * 512 + lane * 8;
    const u16* sp4 = rowp[(g0 + 4) >> 3] + ((g0 + 4) & 7) * 512 + lane * 8;
    const u16* sp5 = rowp[(g0 + 5) >> 3] + ((g0 + 5) & 7) * 512 + lane * 8;
    const int dq0 = ((g0 + 0) >> 3) * 4096 + ((g0 + 0) & 7) * 512;
    const int dq1 = ((g0 + 1) >> 3) * 4096 + ((g0 + 1) & 7) * 512;
    const int dq2 = ((g0 + 2) >> 3) * 4096 + ((g0 + 2) & 7) * 512;
    const int dq3 = ((g0 + 3) >> 3) * 4096 + ((g0 + 3) & 7) * 512;
    const int dq4 = ((g0 + 4) >> 3) * 4096 + ((g0 + 4) & 7) * 512;
    const int dq5 = ((g0 + 5) >> 3) * 4096 + ((g0 + 5) & 7) * 512;

    f32x16 acc[4][2];
    #pragma unroll
    for (int ti = 0; ti < 4; ++ti)
        #pragma unroll
        for (int u = 0; u < 2; ++u)
            #pragma unroll
            for (int r = 0; r < 16; ++r) acc[ti][u][r] = 0.0f;

    // ---- prologue: issue chunks 0 and 1 (12 outstanding per wave) ----
    ISSUE(0, 0);
    ISSUE(1, 12288);

    // ---- 8 chunks, counted-vmcnt ring pipeline, 1 barrier/chunk ----
    DOCHUNK(0); DOCHUNK(1); DOCHUNK(2); DOCHUNK(3);
    DOCHUNK(4); DOCHUNK(5); DOCHUNK(6); DOCHUNK(7);

    // ---- epilogue: pair pp owned by waves (pp,c=0),(pp,c=1) ----
    float vmin = acc[0][0][0], vmax = vmin;
    #pragma unroll
    for (int ti = 0; ti < 4; ++ti)
        #pragma unroll
        for (int u = 0; u < 2; ++u)
            #pragma unroll
            for (int r = 0; r < 16; ++r) {
                vmin = fminf(vmin, acc[ti][u][r]);
                vmax = fmaxf(vmax, acc[ti][u][r]);
            }
    #pragma unroll
    for (int off = 1; off < 64; off <<= 1) {
        vmin = fminf(vmin, __shfl_xor(vmin, off, 64));
        vmax = fmaxf(vmax, __shfl_xor(vmax, off, 64));
    }
    if (lane == 0) { smin[w] = vmin; smax[w] = vmax; }
    __syncthreads();
    const float pmn = fminf(smin[pp * 2], smin[pp * 2 + 1]);
    const float pmx = fmaxf(smax[pp * 2], smax[pp * 2 + 1]);
    const float denom = (pmx > pmn) ? (pmx - pmn) : 1.0f;
    const float scale = 8.0f / denom;
    const float bias  = -pmn * scale;

    // per-thread packed histogram: 128 values -> 8-bit fields (<=128/bin)
    unsigned w0 = 0, w1 = 0;
    #pragma unroll
    for (int ti = 0; ti < 4; ++ti)
        #pragma unroll
        for (int u = 0; u < 2; ++u)
            #pragma unroll
            for (int r = 0; r < 16; ++r) {
                const float t = fmaf(acc[ti][u][r], scale, bias);
                int k = (int)t;          // t >= -eps; trunc == floor
                k = k > 7 ? 7 : k;
                const unsigned inc = 1u << ((k & 3) * 8);
                if (k < 4) w0 += inc; else w1 += inc;
            }
    unsigned e0 = (w0 & 0xFFu)         | (((w0 >> 8)  & 0xFFu) << 16);
    unsigned e1 = ((w0 >> 16) & 0xFFu) | (((w0 >> 24) & 0xFFu) << 16);
    unsigned e2 = (w1 & 0xFFu)         | (((w1 >> 8)  & 0xFFu) << 16);
    unsigned e3 = ((w1 >> 16) & 0xFFu) | (((w1 >> 24) & 0xFFu) << 16);
    #pragma unroll
    for (int off = 32; off > 0; off >>= 1) {
        e0 += __shfl_down(e0, off, 64);
        e1 += __shfl_down(e1, off, 64);
        e2 += __shfl_down(e2, off, 64);
        e3 += __shfl_down(e3, off, 64);
    }
    if (lane == 0) {
        atomicAdd(&hist[pp][0], (int)(e0 & 0xFFFFu)); atomicAdd(&hist[pp][1], (int)(e0 >> 16));
        atomicAdd(&hist[pp][2], (int)(e1 & 0xFFFFu)); atomicAdd(&hist[pp][3], (int)(e1 >> 16));
        atomicAdd(&hist[pp][4], (int)(e2 & 0xFFFFu)); atomicAdd(&hist[pp][5], (int)(e2 >> 16));
        atomicAdd(&hist[pp][6], (int)(e3 & 0xFFFFu)); atomicAdd(&hist[pp][7], (int)(e3 >> 16));
    }
    __syncthreads();

    // one wave per pair normalizes and writes both symmetric rows
    const int B = (pp == 0) ? b1 : b2;
    const bool valid = (pp == 0) || b2valid;
    if (valid && c == 0 && lane < 8) {
        float ss = 0.0f;
        #pragma unroll
        for (int k = 0; k < 8; ++k) {
            const float cc = (float)hist[pp][k];
            ss += cc * cc;
        }
        const float nrm = fmaxf(sqrtf(ss), 1e-12f);
        const float v = (float)hist[pp][lane] / nrm;
        out[((size_t)a * BS + B) * 16 + mat * 8 + lane] = v;
        if (a != B)
            out[((size_t)B * BS + a) * 16 + mat * 8 + lane] = v;
    }
}

extern "C" void kernel_launch(void* const* d_in, const int* in_sizes, int n_in,
                              void* d_out, int out_size, void* d_ws, size_t ws_size,
                              hipStream_t stream) {
    const float* m1 = (const float*)d_in[0];
    const float* m2 = (const float*)d_in[1];
    float* out = (float*)d_out;

    // Workspace: granule-major fp16 array, 2*64*128*256 u16 = 8.39 MB.
    u16* hT = (u16*)d_ws;

    convert_f16_kernel<<<dim3(128, 4), 256, 0, stream>>>(m1, m2, hT);
    gram_hist_mfma<<<2 * NBP, 256, 0, stream>>>(hT, out);
}

// Round 12
// 117.540 us; speedup vs baseline: 1.0561x; 1.0269x over previous
//
#include <hip/hip_runtime.h>
#include <math.h>

// Problem constants (from reference setup_inputs)
#define BS 64      // batch
#define F  256     // features (K of the Gram matmul)
#define M  128     // columns  (M=N of the Gram matmul)
#define MF (M * F) // u16 elements per matrix in hT
#define NBP 1056   // (b-pair, a) tiles per mat: sum_u (2u+2), u=0..31

typedef unsigned short u16;
typedef _Float16 f16x8 __attribute__((ext_vector_type(8)));
typedef float    f32x16 __attribute__((ext_vector_type(16)));

// ---------------------------------------------------------------------------
// Pre-pass: fp32 [f][m] -> fp16 GRANULE-MAJOR hT[b][f8][m][8].
// ---------------------------------------------------------------------------
__global__ __launch_bounds__(256) void convert_f16_kernel(
    const float* __restrict__ m1, const float* __restrict__ m2,
    u16* __restrict__ hT)
{
    __shared__ float tile[64 * M];   // 32 KB
    const int mat = blockIdx.x >> 6;
    const int b   = blockIdx.x & 63;
    const int f0  = blockIdx.y * 64;
    const float* src = (mat == 0 ? m1 : m2) + (size_t)b * MF + (size_t)f0 * M;
    const int tid = threadIdx.x;

    const float4* g = (const float4*)src;
    float4* s = (float4*)tile;
    #pragma unroll
    for (int i = 0; i < 8; ++i)
        s[tid + i * 256] = g[tid + i * 256];
    __syncthreads();

    const size_t obase = ((size_t)(mat * BS + b) * 32 + (f0 >> 3)) * 1024;
    #pragma unroll
    for (int it = 0; it < 4; ++it) {
        const int idx = it * 256 + tid;
        const int f8l = idx >> 7;
        const int m   = idx & 127;
        u16 hh[8] __attribute__((aligned(16)));
        #pragma unroll
        for (int j = 0; j < 8; ++j) {
            const float x = tile[(f8l * 8 + j) * M + m];  // 2 lanes/bank: free
            const _Float16 h = (_Float16)x;               // RNE
            hh[j] = __builtin_bit_cast(u16, h);
        }
        *(uint4*)&hT[obase + (size_t)idx * 8] = *(const uint4*)hh;
    }
}

// ---------------------------------------------------------------------------
// ROUND 20: B-PAIR-MAJOR TILE ORDER (L2 request-merge experiment).
// Status after 12 structure experiments: service rate for our access
// pattern pins at 7.6-8.8 TB/s chip (all schedule/path/occupancy/byte
// variants neutral or worse); kernels that exceed it on this chip (m201
// GEMM 11.6 TB/s, hipBLASLt ~15) have concurrent blocks reading the SAME
// operand panels -> same-line requests merge/multicast in the TCC queues.
// Our old mapping (a-major: b1 = a+2p) gives concurrent blocks DISTINCT
// B rows -> 2/3 of traffic unmergeable; only A (1/3) was shared.
// THIS ROUND: pure remap of the proven 53.4-us kernel (r14; inner loop
// byte-identical): tile = (u, a) with b1=2u, b2=2u+1, a = 0..2u+1 walking
// within the group. Consecutive slots -- and the ~32 concurrently-resident
// blocks of an XCD (groups are up to 64 slots long) -- read the SAME two
// B rows: 2/3 of bytes now mergeable at L2; the 2 co-resident blocks per
// CU read the same B granules within a chunk-period -> L1 hits possible
// on the B-direct fragment loads too. Coverage: b even via pp=0 of u=b/2,
// b odd via pp=1 of u=(b-1)/2, exactly once; sum(2u+2)=1056 per mat.
// Edge a=2u+1: no valid b1 -> duplicate b2's work, suppress pp=0 writes.
// Read-out: 40-47 us = merge real (push further next); 52-54 = every
// mechanism exhausted -> declare roofline: 405 MB register-floor bytes /
// 7.6 TB/s distinct-stream L2 service = 53 us (measured 53.0-53.4 across
// four independent structures).
// ---------------------------------------------------------------------------

#define LOADB(DST, CH) {                                      \
    const u16* pbk = pb + (CH) * 4096;                        \
    DST[0][0] = *(const f16x8*)(pbk);                         \
    DST[0][1] = *(const f16x8*)(pbk + 256);                   \
    DST[1][0] = *(const f16x8*)(pbk + 2048);                  \
    DST[1][1] = *(const f16x8*)(pbk + 2048 + 256);            \
}

__global__ __launch_bounds__(256, 2) void gram_hist_mfma(
    const u16* __restrict__ hT, float* __restrict__ out)
{
    __shared__ u16 lds[2 * 4096];   // 16 KB: A tiles only, double-buffered
    __shared__ float smin[4], smax[4];
    __shared__ int hist[2][8];

    const int tid  = threadIdx.x;
    const int lane = tid & 63;
    const int w    = tid >> 6;

    if (tid < 16) hist[tid >> 3][tid & 7] = 0;

    // XCD-pinned mapping: 2112 blocks = 8 XCDs x 264 slots (r14: HBM -2.5x).
    const int bid  = blockIdx.x;
    const int xcd  = bid & 7;
    const int mat  = xcd >> 2;
    int p = (xcd & 3) * 264 + (bid >> 3);
    // b-pair-major decode: group u (rows b1=2u, b2=2u+1) has 2u+2 slots,
    // slot within group = a (0..2u+1). Consecutive slots share the B rows.
    int u_ = 0;
    { int cnt = 2; while (p >= cnt) { p -= cnt; ++u_; cnt += 2; } }
    const int a  = p;
    const int b2 = 2 * u_ + 1;
    int b1 = 2 * u_;
    const bool b1valid = (a <= b1);
    if (!b1valid) b1 = b2;          // duplicate work, writes suppressed

    const int pp = w >> 1;     // which pair (0: b1, 1: b2)
    const int c  = w & 1;      // which 64-col half
    const int l31   = lane & 31;
    const int lhalf = lane >> 5;

    // A staging: one uint4 x 2 per thread per chunk.
    const u16* pa = hT + (size_t)(mat * BS + a) * MF + tid * 8;
    const int d0 = tid * 8;            // A, first 256 granules
    const int d1 = (256 + tid) * 8;    // A, second

    // B fragment per-lane global base (u16 units):
    //   frag(it,kk,u) = pb + it*4096 + kk*2048 + u*256
    const int bsel = pp ? b2 : b1;
    const u16* pb = hT + (size_t)(mat * BS + bsel) * MF
                  + (size_t)(lhalf * 1024 + c * 512 + l31 * 8);

    f32x16 acc[4][2];
    #pragma unroll
    for (int ti = 0; ti < 4; ++ti)
        #pragma unroll
        for (int u = 0; u < 2; ++u)
            #pragma unroll
            for (int r = 0; r < 16; ++r) acc[ti][u][r] = 0.0f;

    uint4 r0, r1;
    f16x8 bA[2][2], bB[2][2];   // double-buffered B fragment sets

    // ---- prologue: A chunk 0 -> LDS, B frags chunk 0 -> bA ----
    r0 = *(const uint4*)(pa);
    r1 = *(const uint4*)(pa + 2048);
    LOADB(bA, 0);
    *(uint4*)&lds[d0] = r0;
    *(uint4*)&lds[d1] = r1;
    __syncthreads();

    #pragma unroll
    for (int itp = 0; itp < 4; ++itp) {
        // even it = 2*itp, cur = buf0: prefetch chunk 2*itp+1 into bB/buf1
        {
            const int nxt = 2 * itp + 1;
            r0 = *(const uint4*)(pa + nxt * 4096);
            r1 = *(const uint4*)(pa + nxt * 4096 + 2048);
            LOADB(bB, nxt);

            const int cur = 0;
            #pragma unroll
            for (int kk = 0; kk < 2; ++kk) {
                const int base = cur + kk * 2048 + lhalf * 1024 + l31 * 8;
                f16x8 af[4];
                #pragma unroll
                for (int t = 0; t < 4; ++t)
                    af[t] = *(const f16x8*)&lds[base + t * 256];
                #pragma unroll
                for (int ti = 0; ti < 4; ++ti) {
                    acc[ti][0] = __builtin_amdgcn_mfma_f32_32x32x16_f16(af[ti], bA[kk][0], acc[ti][0], 0, 0, 0);
                    acc[ti][1] = __builtin_amdgcn_mfma_f32_32x32x16_f16(af[ti], bA[kk][1], acc[ti][1], 0, 0, 0);
                }
            }
            *(uint4*)&lds[4096 + d0] = r0;
            *(uint4*)&lds[4096 + d1] = r1;
            __syncthreads();
        }
        // odd it = 2*itp+1, cur = buf1: prefetch chunk 2*itp+2 into bA/buf0
        {
            if (itp < 3) {
                const int nxt = 2 * itp + 2;
                r0 = *(const uint4*)(pa + nxt * 4096);
                r1 = *(const uint4*)(pa + nxt * 4096 + 2048);
                LOADB(bA, nxt);
            }
            const int cur = 4096;
            #pragma unroll
            for (int kk = 0; kk < 2; ++kk) {
                const int base = cur + kk * 2048 + lhalf * 1024 + l31 * 8;
                f16x8 af[4];
                #pragma unroll
                for (int t = 0; t < 4; ++t)
                    af[t] = *(const f16x8*)&lds[base + t * 256];
                #pragma unroll
                for (int ti = 0; ti < 4; ++ti) {
                    acc[ti][0] = __builtin_amdgcn_mfma_f32_32x32x16_f16(af[ti], bB[kk][0], acc[ti][0], 0, 0, 0);
                    acc[ti][1] = __builtin_amdgcn_mfma_f32_32x32x16_f16(af[ti], bB[kk][1], acc[ti][1], 0, 0, 0);
                }
            }
            if (itp < 3) {
                *(uint4*)&lds[d0] = r0;
                *(uint4*)&lds[d1] = r1;
                __syncthreads();
            }
        }
    }

    // ---- epilogue: pair pp owned by waves (pp,c=0),(pp,c=1) ----
    float vmin = acc[0][0][0], vmax = vmin;
    #pragma unroll
    for (int ti = 0; ti < 4; ++ti)
        #pragma unroll
        for (int u = 0; u < 2; ++u)
            #pragma unroll
            for (int r = 0; r < 16; ++r) {
                vmin = fminf(vmin, acc[ti][u][r]);
                vmax = fmaxf(vmax, acc[ti][u][r]);
            }
    #pragma unroll
    for (int off = 1; off < 64; off <<= 1) {
        vmin = fminf(vmin, __shfl_xor(vmin, off, 64));
        vmax = fmaxf(vmax, __shfl_xor(vmax, off, 64));
    }
    if (lane == 0) { smin[w] = vmin; smax[w] = vmax; }
    __syncthreads();
    const float pmn = fminf(smin[pp * 2], smin[pp * 2 + 1]);
    const float pmx = fmaxf(smax[pp * 2], smax[pp * 2 + 1]);
    const float denom = (pmx > pmn) ? (pmx - pmn) : 1.0f;
    const float scale = 8.0f / denom;
    const float bias  = -pmn * scale;

    // per-thread packed histogram: 128 values -> 8-bit fields (<=128/bin)
    unsigned w0 = 0, w1 = 0;
    #pragma unroll
    for (int ti = 0; ti < 4; ++ti)
        #pragma unroll
        for (int u = 0; u < 2; ++u)
            #pragma unroll
            for (int r = 0; r < 16; ++r) {
                const float t = fmaf(acc[ti][u][r], scale, bias);
                int k = (int)t;          // t >= -eps; trunc == floor
                k = k > 7 ? 7 : k;
                const unsigned inc = 1u << ((k & 3) * 8);
                if (k < 4) w0 += inc; else w1 += inc;
            }
    unsigned e0 = (w0 & 0xFFu)         | (((w0 >> 8)  & 0xFFu) << 16);
    unsigned e1 = ((w0 >> 16) & 0xFFu) | (((w0 >> 24) & 0xFFu) << 16);
    unsigned e2 = (w1 & 0xFFu)         | (((w1 >> 8)  & 0xFFu) << 16);
    unsigned e3 = ((w1 >> 16) & 0xFFu) | (((w1 >> 24) & 0xFFu) << 16);
    #pragma unroll
    for (int off = 32; off > 0; off >>= 1) {
        e0 += __shfl_down(e0, off, 64);
        e1 += __shfl_down(e1, off, 64);
        e2 += __shfl_down(e2, off, 64);
        e3 += __shfl_down(e3, off, 64);
    }
    if (lane == 0) {
        atomicAdd(&hist[pp][0], (int)(e0 & 0xFFFFu)); atomicAdd(&hist[pp][1], (int)(e0 >> 16));
        atomicAdd(&hist[pp][2], (int)(e1 & 0xFFFFu)); atomicAdd(&hist[pp][3], (int)(e1 >> 16));
        atomicAdd(&hist[pp][4], (int)(e2 & 0xFFFFu)); atomicAdd(&hist[pp][5], (int)(e2 >> 16));
        atomicAdd(&hist[pp][6], (int)(e3 & 0xFFFFu)); atomicAdd(&hist[pp][7], (int)(e3 >> 16));
    }
    __syncthreads();

    // one wave per pair normalizes and writes both symmetric rows
    const int B = (pp == 0) ? b1 : b2;
    const bool valid = (pp == 1) || b1valid;
    if (valid && c == 0 && lane < 8) {
        float ss = 0.0f;
        #pragma unroll
        for (int k = 0; k < 8; ++k) {
            const float cc = (float)hist[pp][k];
            ss += cc * cc;
        }
        const float nrm = fmaxf(sqrtf(ss), 1e-12f);
        const float v = (float)hist[pp][lane] / nrm;
        out[((size_t)a * BS + B) * 16 + mat * 8 + lane] = v;
        if (a != B)
            out[((size_t)B * BS + a) * 16 + mat * 8 + lane] = v;
    }
}

extern "C" void kernel_launch(void* const* d_in, const int* in_sizes, int n_in,
                              void* d_out, int out_size, void* d_ws, size_t ws_size,
                              hipStream_t stream) {
    const float* m1 = (const float*)d_in[0];
    const float* m2 = (const float*)d_in[1];
    float* out = (float*)d_out;

    // Workspace: granule-major fp16 array, 2*64*128*256 u16 = 8.39 MB.
    u16* hT = (u16*)d_ws;

    convert_f16_kernel<<<dim3(128, 4), 256, 0, stream>>>(m1, m2, hT);
    gram_hist_mfma<<<2 * NBP, 256, 0, stream>>>(hT, out);
}